// Round 5
// baseline (311.686 us; speedup 1.0000x reference)
//
#include <hip/hip_runtime.h>
#include <stdint.h>

// ---------------------------------------------------------------------------
// MultiHeadSelfAttention: B=8, N=1024, D=1024, H=16, hd=64, scale=0.125
// Pipeline: [x->bf16, wT->bf16] -> GEMM1(qkv + bias, scatter Q/K(pre-scaled)/Vt)
//           -> flash attention (swapped QK^T, in-lane softmax, exp2 units)
//           -> GEMM2(proj + bias, fp32 out)
// GEMMs: 256xBN deep-pipelined 8-wave kernel (counted vmcnt(2) + BARRIER
// before dependent ds_reads [R4 race fix], per-phase barriers, XOR-swizzled
// LDS via pre-swizzled global source, setprio MFMA).
// ---------------------------------------------------------------------------

typedef short bf16x8 __attribute__((ext_vector_type(8)));
typedef float f32x4 __attribute__((ext_vector_type(4)));
typedef uint32_t u32x2 __attribute__((ext_vector_type(2)));

__device__ __forceinline__ short f32_bf16(float f) {
  uint32_t u = __builtin_bit_cast(uint32_t, f);
  u += 0x7FFFu + ((u >> 16) & 1u);   // round-to-nearest-even (no NaN inputs)
  return (short)(u >> 16);
}

__device__ __forceinline__ float exp2_fast(float x) {
  float r; asm("v_exp_f32 %0, %1" : "=v"(r) : "v"(x)); return r;
}

__device__ __forceinline__ uint32_t cvt_pk_bf16(float lo, float hi) {
  uint32_t r;
  asm("v_cvt_pk_bf16_f32 %0, %1, %2" : "=v"(r) : "v"(lo), "v"(hi));
  return r;
}

__device__ __forceinline__ void gload_lds16(const void* g, void* l) {
  __builtin_amdgcn_global_load_lds(
      (const __attribute__((address_space(1))) uint32_t*)g,
      (__attribute__((address_space(3))) uint32_t*)l, 16, 0, 0);
}

// ---------------------------------------------------------------- prep ------
__global__ __launch_bounds__(256) void convert_x_kernel(
    const float* __restrict__ x, short* __restrict__ xb) {
  int i = blockIdx.x * 256 + threadIdx.x;
  const float4 f0 = ((const float4*)x)[i * 2];
  const float4 f1 = ((const float4*)x)[i * 2 + 1];
  bf16x8 o;
  o[0] = f32_bf16(f0.x); o[1] = f32_bf16(f0.y);
  o[2] = f32_bf16(f0.z); o[3] = f32_bf16(f0.w);
  o[4] = f32_bf16(f1.x); o[5] = f32_bf16(f1.y);
  o[6] = f32_bf16(f1.z); o[7] = f32_bf16(f1.w);
  ((bf16x8*)xb)[i] = o;
}

// w: fp32 [1024][N] -> wt: bf16 [N][1024]
__global__ __launch_bounds__(256) void transpose_w_kernel(
    const float* __restrict__ w, short* __restrict__ wt, int N) {
  __shared__ float tile[64][65];
  const int n0 = blockIdx.x * 64, k0 = blockIdx.y * 64;
  const int tr = threadIdx.x >> 6, tc = threadIdx.x & 63;
#pragma unroll
  for (int i = 0; i < 16; ++i) {
    int k = tr + i * 4;
    tile[k][tc] = w[(size_t)(k0 + k) * N + n0 + tc];
  }
  __syncthreads();
#pragma unroll
  for (int i = 0; i < 16; ++i) {
    int a = tr + i * 4;
    wt[(size_t)(n0 + a) * 1024 + k0 + tc] = f32_bf16(tile[tc][a]);
  }
}

// ------------------------------------------------- deep-pipelined GEMM -----
// BM=256 x BN, BK=64, 512 threads (8 waves, 2M x 4N), per-wave 128 x BN/4.
// Per K-tile: 4 phases (C-quadrants). Tile t+1 staged 2 chunks/phase into
// buf^1 while computing buf. Phase 0: s_waitcnt vmcnt(2) [drains ALL of this
// wave's tile-t chunks] + s_barrier [-> ALL waves' tile-t chunks resident]
// BEFORE any ds_read of buf. Raw s_barrier per phase otherwise (no vmcnt
// drain). LDS reads 8-way-max via XOR swizzle: LDS[r][s] holds global
// granule s^(r&7) (pre-swizzled gload source, rule #21).
// EPI=0: qkv scatter epilogue (bias, Q/K-prescaled/Vt). EPI=1: fp32 out+bias.
template <int BN, int NREP, int BCH, int EPI>
__global__ __launch_bounds__(512, 2) void gemm8_kernel(
    const short* __restrict__ A, const short* __restrict__ Bt,
    const float* __restrict__ bias, short* __restrict__ Qb,
    short* __restrict__ Kb, short* __restrict__ Vt, float* __restrict__ out,
    int NTN) {
  __shared__ short Asm[2][256 * 64];
  __shared__ short Bsm[2][BN * 64];

  constexpr int TOT = 4 + BCH;               // staging chunks per K-tile
  constexpr int CS2 = (TOT == 8) ? 6 : 5;    // phase chunk split
  constexpr int NPP = NREP / 2;              // n-frags per phase
  constexpr int WN = NREP * 16;              // per-wave N extent

  const int tid = threadIdx.x;
  const int lane = tid & 63;
  const int w = tid >> 6;
  const int wm = w >> 2, wn = w & 3;
  const int c = lane & 15, g = lane >> 4;

  // XCD-bijective swizzle (grid % 8 == 0 for both instantiations)
  const int nwg = gridDim.x;
  const int wg = (blockIdx.x & 7) * (nwg >> 3) + (blockIdx.x >> 3);
  const int tm = wg / NTN, tn = wg % NTN;
  const int m0 = tm * 256, n0 = tn * BN;

  f32x4 acc[8][NREP] = {};

  auto stage_chunk = [&](int ci, int dbuf, int kk0) {
    if (ci < 4) {
      const int p = ci * 512 + tid;
      const int r = p >> 3, s = p & 7;
      gload_lds16(A + (size_t)(m0 + r) * 1024 + kk0 + ((s ^ (r & 7)) * 8),
                  &Asm[dbuf][p * 8]);
    } else {
      const int p = (ci - 4) * 512 + tid;
      const int r = p >> 3, s = p & 7;
      gload_lds16(Bt + (size_t)(n0 + r) * 1024 + kk0 + ((s ^ (r & 7)) * 8),
                  &Bsm[dbuf][p * 8]);
    }
  };

  // prologue: stage tile 0 into buf0
#pragma unroll
  for (int ci = 0; ci < TOT; ++ci) stage_chunk(ci, 0, 0);

  auto tile_step = [&](int t, int buf) {
#pragma unroll
    for (int p4 = 0; p4 < 4; ++p4) {
      // stage tile t+1's chunks for this phase into buf^1
      const int cs = (p4 == 0) ? 0 : (p4 == 1) ? 2 : (p4 == 2) ? 4 : CS2;
      const int ce = (p4 == 0) ? 2 : (p4 == 1) ? 4 : (p4 == 2) ? CS2 : TOT;
      if (t < 15) {
#pragma unroll
        for (int ci = cs; ci < ce; ++ci) stage_chunk(ci, buf ^ 1, (t + 1) * 64);
      }
      if (p4 == 0) {
        // Drain this wave's tile-t chunks (newest 2 = tile t+1's, stay in
        // flight), then BARRIER so every wave's tile-t chunks are resident
        // before any dependent ds_read below. [R4 fix: barrier was missing
        // -> cross-wave stale-LDS race, absmax 3.8e-2]
        if (t < 15) asm volatile("s_waitcnt vmcnt(2)" ::: "memory");
        else        asm volatile("s_waitcnt vmcnt(0)" ::: "memory");
        __builtin_amdgcn_s_barrier();
      }
      const int mq = p4 >> 1, nq = p4 & 1;
      bf16x8 af[4][2];
      bf16x8 bfr[NPP][2];
#pragma unroll
      for (int mm = 0; mm < 4; ++mm) {
        const int R = wm * 128 + (mq * 4 + mm) * 16 + c;
#pragma unroll
        for (int kk = 0; kk < 2; ++kk)
          af[mm][kk] = *(const bf16x8*)&Asm[buf][R * 64 + (((kk * 4 + g) ^ (c & 7)) * 8)];
      }
#pragma unroll
      for (int jn = 0; jn < NPP; ++jn) {
        const int S = wn * WN + (nq * NPP + jn) * 16 + c;
#pragma unroll
        for (int kk = 0; kk < 2; ++kk)
          bfr[jn][kk] = *(const bf16x8*)&Bsm[buf][S * 64 + (((kk * 4 + g) ^ (c & 7)) * 8)];
      }
      __builtin_amdgcn_s_barrier();
      asm volatile("s_waitcnt lgkmcnt(0)" ::: "memory");
      __builtin_amdgcn_sched_barrier(0);
      __builtin_amdgcn_s_setprio(1);
#pragma unroll
      for (int mm = 0; mm < 4; ++mm)
#pragma unroll
        for (int jn = 0; jn < NPP; ++jn)
#pragma unroll
          for (int kk = 0; kk < 2; ++kk)
            acc[mq * 4 + mm][nq * NPP + jn] = __builtin_amdgcn_mfma_f32_16x16x32_bf16(
                af[mm][kk], bfr[jn][kk], acc[mq * 4 + mm][nq * NPP + jn], 0, 0, 0);
      __builtin_amdgcn_s_setprio(0);
      __builtin_amdgcn_s_barrier();
    }
  };

  for (int t2 = 0; t2 < 16; t2 += 2) {
    tile_step(t2, 0);
    tile_step(t2 + 1, 1);
  }

  // epilogue
#pragma unroll
  for (int mm = 0; mm < 8; ++mm) {
    const int i_base = m0 + wm * 128 + mm * 16 + 4 * g;
#pragma unroll
    for (int nn = 0; nn < NREP; ++nn) {
      const int j = n0 + wn * WN + nn * 16 + c;
      const float bj = bias[j];
      if (EPI == 0) {
        const int three = j >> 10, rem = j & 1023, h = rem >> 6, d = rem & 63;
        const float sc = (three == 1) ? 0.18033688f : 1.0f;  // 0.125*log2(e)
#pragma unroll
        for (int r = 0; r < 4; ++r) {
          const int i = i_base + r;
          const int bb = i >> 10, nnq = i & 1023;
          const int bh = bb * 16 + h;
          const short bv = f32_bf16((acc[mm][nn][r] + bj) * sc);
          if (three == 0)
            Qb[(size_t)(bh * 1024 + nnq) * 64 + d] = bv;
          else if (three == 1)
            Kb[(size_t)(bh * 1024 + nnq) * 64 + d] = bv;
          else
            Vt[(size_t)(bh * 64 + d) * 1024 + nnq] = bv;
        }
      } else {
#pragma unroll
        for (int r = 0; r < 4; ++r)
          out[(size_t)(i_base + r) * 1024 + j] = acc[mm][nn][r] + bj;
      }
    }
  }
}

// ----------------------------------------------------------- attention -----
// One block = 128 q-rows of one (b,h). 4 waves x 32 rows. KV tile = 64 keys.
// Swapped QK^T: lane holds 16 keys of ONE query; softmax reduce = 15 fmax +
// 2 shfl; defer-max; exp2 units (K pre-scaled); P via cvt_pk to LDS; T14
// async staging of next K/V tile.
__global__ __launch_bounds__(256, 2) void attn_kernel(
    const short* __restrict__ Qb, const short* __restrict__ Kb,
    const short* __restrict__ Vt, short* __restrict__ Ao) {
  __shared__ __align__(16) char smem[25600];
  short* Kf = (short*)smem;                 // 8 planes x 64 lanes x 8 bf16
  short* Vf = (short*)(smem + 8192);
  short* Pl = (short*)(smem + 16384);       // 4 waves x [16 q][72]

  const int tid = threadIdx.x, lane = tid & 63, w = tid >> 6;
  const int c = lane & 15, g = lane >> 4;
  const int bh = blockIdx.x >> 3, qb = blockIdx.x & 7;
  const int bb = bh >> 4, h = bh & 15;
  const int q0 = qb * 128 + w * 32;

  bf16x8 qf[2][2];
#pragma unroll
  for (int m = 0; m < 2; ++m)
#pragma unroll
    for (int ks = 0; ks < 2; ++ks)
      qf[m][ks] = *(const bf16x8*)(Qb + (size_t)(bh * 1024 + q0 + m * 16 + c) * 64 + ks * 32 + 8 * g);

  f32x4 o[2][4] = {};
  float mrun[2] = {-3.0e38f, -3.0e38f};
  float lrun[2] = {0.f, 0.f};

  const int row_r = tid >> 2, seg = tid & 3;
  const short* kp = Kb + (size_t)(bh * 1024 + row_r) * 64 + seg * 16;
  const short* vp = Vt + (size_t)(bh * 64 + row_r) * 1024 + seg * 16;
  short *kdst0, *kdst1, *vdst0, *vdst1;
  {
    const int d0a = seg * 16, d0b = seg * 16 + 8;
    const int pa = (row_r >> 4) * 2 + (d0a >> 5);
    const int pb = (row_r >> 4) * 2 + (d0b >> 5);
    const int sa = (row_r & 15) + 16 * ((d0a & 31) >> 3);
    const int sb = (row_r & 15) + 16 * ((d0b & 31) >> 3);
    kdst0 = &Kf[(pa * 64 + sa) * 8]; kdst1 = &Kf[(pb * 64 + sb) * 8];
    vdst0 = &Vf[(pa * 64 + sa) * 8]; vdst1 = &Vf[(pb * 64 + sb) * 8];
  }

  uint32_t* plw = (uint32_t*)(Pl + w * 1152);
  const short* plr = Pl + w * 1152;

  auto compute = [&]() {
#pragma unroll
    for (int m = 0; m < 2; ++m) {
      f32x4 s[4];
#pragma unroll
      for (int kt = 0; kt < 4; ++kt) {
        f32x4 sa = {};
#pragma unroll
        for (int ks = 0; ks < 2; ++ks) {
          bf16x8 kb = *(const bf16x8*)&Kf[((kt * 2 + ks) * 64 + lane) * 8];
          sa = __builtin_amdgcn_mfma_f32_16x16x32_bf16(kb, qf[m][ks], sa, 0, 0, 0);
        }
        s[kt] = sa;
      }
      float vmax = s[0][0];
#pragma unroll
      for (int kt = 0; kt < 4; ++kt)
#pragma unroll
        for (int r = 0; r < 4; ++r) vmax = fmaxf(vmax, s[kt][r]);
      vmax = fmaxf(vmax, __shfl_xor(vmax, 16));
      vmax = fmaxf(vmax, __shfl_xor(vmax, 32));
      if (!__all(vmax <= mrun[m] + 8.0f)) {
        float mnew = fmaxf(mrun[m], vmax);
        float al = exp2_fast(mrun[m] - mnew);
        lrun[m] *= al;
#pragma unroll
        for (int dt = 0; dt < 4; ++dt) o[m][dt] *= al;
        mrun[m] = mnew;
      }
      float rs = 0.f;
#pragma unroll
      for (int kt = 0; kt < 4; ++kt) {
        float p0 = exp2_fast(s[kt][0] - mrun[m]);
        float p1 = exp2_fast(s[kt][1] - mrun[m]);
        float p2 = exp2_fast(s[kt][2] - mrun[m]);
        float p3 = exp2_fast(s[kt][3] - mrun[m]);
        rs += (p0 + p1) + (p2 + p3);
        u32x2 pk;
        pk[0] = cvt_pk_bf16(p0, p1);
        pk[1] = cvt_pk_bf16(p2, p3);
        *(u32x2*)&plw[c * 36 + kt * 8 + 2 * g] = pk;
      }
      rs += __shfl_xor(rs, 16);
      rs += __shfl_xor(rs, 32);
      lrun[m] += rs;
#pragma unroll
      for (int kk = 0; kk < 2; ++kk) {
        bf16x8 pb = *(const bf16x8*)(plr + c * 72 + kk * 32 + 8 * g);
#pragma unroll
        for (int dt = 0; dt < 4; ++dt) {
          bf16x8 vb = *(const bf16x8*)&Vf[((dt * 2 + kk) * 64 + lane) * 8];
          o[m][dt] = __builtin_amdgcn_mfma_f32_16x16x32_bf16(vb, pb, o[m][dt], 0, 0, 0);
        }
      }
    }
  };

  bf16x8 ka0, ka1, va0, va1, kc0, kc1, vc0, vc1;
  ka0 = *(const bf16x8*)(kp);     ka1 = *(const bf16x8*)(kp + 8);
  va0 = *(const bf16x8*)(vp);     va1 = *(const bf16x8*)(vp + 8);

  for (int t = 0; t < 16; t += 2) {
    __syncthreads();
    *(bf16x8*)kdst0 = ka0; *(bf16x8*)kdst1 = ka1;
    *(bf16x8*)vdst0 = va0; *(bf16x8*)vdst1 = va1;
    {
      const short* kpt = kp + (size_t)(t + 1) * 4096;
      const short* vpt = vp + (t + 1) * 64;
      kc0 = *(const bf16x8*)(kpt); kc1 = *(const bf16x8*)(kpt + 8);
      vc0 = *(const bf16x8*)(vpt); vc1 = *(const bf16x8*)(vpt + 8);
    }
    __syncthreads();
    compute();
    __syncthreads();
    *(bf16x8*)kdst0 = kc0; *(bf16x8*)kdst1 = kc1;
    *(bf16x8*)vdst0 = vc0; *(bf16x8*)vdst1 = vc1;
    if (t + 2 < 16) {
      const short* kpt = kp + (size_t)(t + 2) * 4096;
      const short* vpt = vp + (t + 2) * 64;
      ka0 = *(const bf16x8*)(kpt); ka1 = *(const bf16x8*)(kpt + 8);
      va0 = *(const bf16x8*)(vpt); va1 = *(const bf16x8*)(vpt + 8);
    }
    __syncthreads();
    compute();
  }

  __syncthreads();
  float* Osc = (float*)smem + w * (16 * 68);
  const int qrow = lane >> 2, dseg = (lane & 3) << 4;
#pragma unroll
  for (int m = 0; m < 2; ++m) {
    const float inv = 1.0f / lrun[m];
#pragma unroll
    for (int dt = 0; dt < 4; ++dt)
#pragma unroll
      for (int r = 0; r < 4; ++r)
        Osc[c * 68 + dt * 16 + 4 * g + r] = o[m][dt][r] * inv;
#pragma unroll
    for (int j = 0; j < 2; ++j) {
      f32x4 a0 = *(f32x4*)&Osc[qrow * 68 + dseg + j * 8];
      f32x4 a1 = *(f32x4*)&Osc[qrow * 68 + dseg + j * 8 + 4];
      bf16x8 ob;
      ob[0] = f32_bf16(a0[0]); ob[1] = f32_bf16(a0[1]);
      ob[2] = f32_bf16(a0[2]); ob[3] = f32_bf16(a0[3]);
      ob[4] = f32_bf16(a1[0]); ob[5] = f32_bf16(a1[1]);
      ob[6] = f32_bf16(a1[2]); ob[7] = f32_bf16(a1[3]);
      *(bf16x8*)(Ao + (size_t)(bb * 1024 + q0 + m * 16 + qrow) * 1024 + h * 64 + dseg + j * 8) = ob;
    }
    __syncthreads();
  }
}

// ------------------------------------------------------------- launch ------
extern "C" void kernel_launch(void* const* d_in, const int* in_sizes, int n_in,
                              void* d_out, int out_size, void* d_ws, size_t ws_size,
                              hipStream_t stream) {
  const float* x = (const float*)d_in[0];
  const float* w_qkv = (const float*)d_in[1];
  const float* b_qkv = (const float*)d_in[2];
  const float* w_proj = (const float*)d_in[3];
  const float* b_proj = (const float*)d_in[4];
  float* out = (float*)d_out;

  char* ws = (char*)d_ws;
  const size_t XB_OFF = 0;                       // 16 MB (reused as attn_out)
  const size_t WQKVT_OFF = 16777216;             // 6 MB
  const size_t WPROJT_OFF = WQKVT_OFF + 6291456; // 2 MB
  const size_t Q_OFF = WPROJT_OFF + 2097152;     // 16 MB
  const size_t K_OFF = Q_OFF + 16777216;         // 16 MB
  const size_t VT_OFF = K_OFF + 16777216;        // 16 MB
  short* xb = (short*)(ws + XB_OFF);
  short* wqkvT = (short*)(ws + WQKVT_OFF);
  short* wprojT = (short*)(ws + WPROJT_OFF);
  short* Qb = (short*)(ws + Q_OFF);
  short* Kb = (short*)(ws + K_OFF);
  short* Vt = (short*)(ws + VT_OFF);
  short* attn_o = xb;  // xb dead after GEMM1

  convert_x_kernel<<<dim3(4096), dim3(256), 0, stream>>>(x, xb);
  transpose_w_kernel<<<dim3(48, 16), dim3(256), 0, stream>>>(w_qkv, wqkvT, 3072);
  transpose_w_kernel<<<dim3(16, 16), dim3(256), 0, stream>>>(w_proj, wprojT, 1024);
  // GEMM1: 8192x3072x1024, 256x256 tiles -> 32x12 = 384 blocks
  gemm8_kernel<256, 4, 4, 0><<<dim3(384), dim3(512), 0, stream>>>(
      xb, wqkvT, b_qkv, Qb, Kb, Vt, nullptr, 12);
  attn_kernel<<<dim3(1024), dim3(256), 0, stream>>>(Qb, Kb, Vt, attn_o);
  // GEMM2: 8192x1024x1024, 256x128 tiles -> 32x8 = 256 blocks (1 full round)
  gemm8_kernel<128, 2, 2, 1><<<dim3(256), dim3(512), 0, stream>>>(
      attn_o, wprojT, b_proj, nullptr, nullptr, nullptr, out, 8);
}

// Round 6
// 284.805 us; speedup vs baseline: 1.0944x; 1.0944x over previous
//
#include <hip/hip_runtime.h>
#include <stdint.h>

// ---------------------------------------------------------------------------
// MultiHeadSelfAttention: B=8, N=1024, D=1024, H=16, hd=64, scale=0.125
// Pipeline: [x->bf16, wT->bf16] -> GEMM1(qkv + bias, scatter Q/K(pre-scaled)/Vt)
//           -> flash attention (swapped QK^T, in-lane softmax, exp2 units)
//           -> GEMM2(proj + bias, fp32 out)
// GEMMs (R6): 256x128 tile, 8 waves, 2 phases/tile, FULL next-tile staging at
// phase 0 + vmcnt(6) (prefetch distance = 1 K-tile), 2 barriers/tile,
// XOR-swizzled LDS (0 conflicts, verified R5), exact grid rounds (768/256).
// ---------------------------------------------------------------------------

typedef short bf16x8 __attribute__((ext_vector_type(8)));
typedef float f32x4 __attribute__((ext_vector_type(4)));
typedef uint32_t u32x2 __attribute__((ext_vector_type(2)));

__device__ __forceinline__ short f32_bf16(float f) {
  uint32_t u = __builtin_bit_cast(uint32_t, f);
  u += 0x7FFFu + ((u >> 16) & 1u);   // round-to-nearest-even (no NaN inputs)
  return (short)(u >> 16);
}

__device__ __forceinline__ float exp2_fast(float x) {
  float r; asm("v_exp_f32 %0, %1" : "=v"(r) : "v"(x)); return r;
}

__device__ __forceinline__ uint32_t cvt_pk_bf16(float lo, float hi) {
  uint32_t r;
  asm("v_cvt_pk_bf16_f32 %0, %1, %2" : "=v"(r) : "v"(lo), "v"(hi));
  return r;
}

__device__ __forceinline__ void gload_lds16(const void* g, void* l) {
  __builtin_amdgcn_global_load_lds(
      (const __attribute__((address_space(1))) uint32_t*)g,
      (__attribute__((address_space(3))) uint32_t*)l, 16, 0, 0);
}

// ---------------------------------------------------------------- prep ------
__global__ __launch_bounds__(256) void convert_x_kernel(
    const float* __restrict__ x, short* __restrict__ xb) {
  int i = blockIdx.x * 256 + threadIdx.x;
  const float4 f0 = ((const float4*)x)[i * 2];
  const float4 f1 = ((const float4*)x)[i * 2 + 1];
  bf16x8 o;
  o[0] = f32_bf16(f0.x); o[1] = f32_bf16(f0.y);
  o[2] = f32_bf16(f0.z); o[3] = f32_bf16(f0.w);
  o[4] = f32_bf16(f1.x); o[5] = f32_bf16(f1.y);
  o[6] = f32_bf16(f1.z); o[7] = f32_bf16(f1.w);
  ((bf16x8*)xb)[i] = o;
}

// w: fp32 [1024][N] -> wt: bf16 [N][1024]
__global__ __launch_bounds__(256) void transpose_w_kernel(
    const float* __restrict__ w, short* __restrict__ wt, int N) {
  __shared__ float tile[64][65];
  const int n0 = blockIdx.x * 64, k0 = blockIdx.y * 64;
  const int tr = threadIdx.x >> 6, tc = threadIdx.x & 63;
#pragma unroll
  for (int i = 0; i < 16; ++i) {
    int k = tr + i * 4;
    tile[k][tc] = w[(size_t)(k0 + k) * N + n0 + tc];
  }
  __syncthreads();
#pragma unroll
  for (int i = 0; i < 16; ++i) {
    int a = tr + i * 4;
    wt[(size_t)(n0 + a) * 1024 + k0 + tc] = f32_bf16(tile[tc][a]);
  }
}

// ------------------------------------------------- deep-pipelined GEMM -----
// BM=256 x BN=128, BK=64, 512 threads (8 waves 2M x 4N), per-wave 128x32.
// Per K-tile: phase 0 stages the ENTIRE next tile (6 gload_lds chunks) into
// buf^1, then vmcnt(6) [drains this wave's CURRENT-tile chunks, issued one
// full tile ago] + s_barrier [all waves drained] before any ds_read of buf.
// Then 2 compute phases (mq halves, 16 MFMA each); B-frags read once.
// End-of-tile s_barrier closes the buf read-before-overwrite hazard.
// LDS reads conflict-free via XOR swizzle: LDS[r][s] holds global granule
// s^(r&7) (pre-swizzled gload source, rule #21; R5 measured 0 conflicts).
// EPI=0: qkv scatter epilogue (bias, Q/K-prescaled/Vt). EPI=1: fp32 out+bias.
template <int EPI>
__global__ __launch_bounds__(512, 1) void gemm8_kernel(
    const short* __restrict__ A, const short* __restrict__ Bt,
    const float* __restrict__ bias, short* __restrict__ Qb,
    short* __restrict__ Kb, short* __restrict__ Vt, float* __restrict__ out,
    int NTN) {
  __shared__ short Asm[2][256 * 64];
  __shared__ short Bsm[2][128 * 64];

  const int tid = threadIdx.x;
  const int lane = tid & 63;
  const int w = tid >> 6;
  const int wm = w >> 2, wn = w & 3;
  const int c = lane & 15, g = lane >> 4;

  // XCD-bijective swizzle (grid % 8 == 0 for both instantiations)
  const int nwg = gridDim.x;
  const int wg = (blockIdx.x & 7) * (nwg >> 3) + (blockIdx.x >> 3);
  const int tm = wg / NTN, tn = wg % NTN;
  const int m0 = tm * 256, n0 = tn * 128;

  f32x4 acc[8][2] = {};

  // 6 chunks/tile: ci 0..3 = A (256x64), ci 4..5 = B (128x64)
  auto stage_chunk = [&](int ci, int dbuf, int kk0) {
    if (ci < 4) {
      const int p = ci * 512 + tid;
      const int r = p >> 3, s = p & 7;
      gload_lds16(A + (size_t)(m0 + r) * 1024 + kk0 + ((s ^ (r & 7)) * 8),
                  &Asm[dbuf][p * 8]);
    } else {
      const int p = (ci - 4) * 512 + tid;
      const int r = p >> 3, s = p & 7;
      gload_lds16(Bt + (size_t)(n0 + r) * 1024 + kk0 + ((s ^ (r & 7)) * 8),
                  &Bsm[dbuf][p * 8]);
    }
  };

  // prologue: stage tile 0 into buf0
#pragma unroll
  for (int ci = 0; ci < 6; ++ci) stage_chunk(ci, 0, 0);

  for (int t = 0; t < 16; ++t) {
    const int buf = t & 1;
    // ---- phase 0 header: stage ALL of tile t+1, wait for tile t ----
    if (t < 15) {
#pragma unroll
      for (int ci = 0; ci < 6; ++ci) stage_chunk(ci, buf ^ 1, (t + 1) * 64);
      asm volatile("s_waitcnt vmcnt(6)" ::: "memory");
    } else {
      asm volatile("s_waitcnt vmcnt(0)" ::: "memory");
    }
    __builtin_amdgcn_s_barrier();        // all waves' tile-t chunks resident
    __builtin_amdgcn_sched_barrier(0);   // keep ds_reads below the barrier

    // B-frags: read once, held across both phases
    bf16x8 bfr[2][2];
#pragma unroll
    for (int jn = 0; jn < 2; ++jn) {
      const int S = wn * 32 + jn * 16 + c;
#pragma unroll
      for (int kk = 0; kk < 2; ++kk)
        bfr[jn][kk] = *(const bf16x8*)&Bsm[buf][S * 64 + (((kk * 4 + g) ^ (c & 7)) * 8)];
    }
    // ---- 2 compute phases: mq halves of the wave's 128 rows ----
#pragma unroll
    for (int mq = 0; mq < 2; ++mq) {
      bf16x8 af[4][2];
#pragma unroll
      for (int mm = 0; mm < 4; ++mm) {
        const int R = wm * 128 + (mq * 4 + mm) * 16 + c;
#pragma unroll
        for (int kk = 0; kk < 2; ++kk)
          af[mm][kk] = *(const bf16x8*)&Asm[buf][R * 64 + (((kk * 4 + g) ^ (c & 7)) * 8)];
      }
      asm volatile("s_waitcnt lgkmcnt(0)" ::: "memory");
      __builtin_amdgcn_sched_barrier(0);  // rule #18: don't hoist MFMA above
      __builtin_amdgcn_s_setprio(1);
#pragma unroll
      for (int mm = 0; mm < 4; ++mm)
#pragma unroll
        for (int jn = 0; jn < 2; ++jn)
#pragma unroll
          for (int kk = 0; kk < 2; ++kk)
            acc[mq * 4 + mm][jn] = __builtin_amdgcn_mfma_f32_16x16x32_bf16(
                af[mm][kk], bfr[jn][kk], acc[mq * 4 + mm][jn], 0, 0, 0);
      __builtin_amdgcn_s_setprio(0);
    }
    __builtin_amdgcn_s_barrier();        // all reads of buf done before t+1
    __builtin_amdgcn_sched_barrier(0);   // keep next staging below
  }

  // epilogue
#pragma unroll
  for (int mm = 0; mm < 8; ++mm) {
    const int i_base = m0 + wm * 128 + mm * 16 + 4 * g;
#pragma unroll
    for (int nn = 0; nn < 2; ++nn) {
      const int j = n0 + wn * 32 + nn * 16 + c;
      const float bj = bias[j];
      if (EPI == 0) {
        const int three = j >> 10, rem = j & 1023, h = rem >> 6, d = rem & 63;
        const float sc = (three == 1) ? 0.18033688f : 1.0f;  // 0.125*log2(e)
#pragma unroll
        for (int r = 0; r < 4; ++r) {
          const int i = i_base + r;
          const int bb = i >> 10, nnq = i & 1023;
          const int bh = bb * 16 + h;
          const short bv = f32_bf16((acc[mm][nn][r] + bj) * sc);
          if (three == 0)
            Qb[(size_t)(bh * 1024 + nnq) * 64 + d] = bv;
          else if (three == 1)
            Kb[(size_t)(bh * 1024 + nnq) * 64 + d] = bv;
          else
            Vt[(size_t)(bh * 64 + d) * 1024 + nnq] = bv;
        }
      } else {
#pragma unroll
        for (int r = 0; r < 4; ++r)
          out[(size_t)(i_base + r) * 1024 + j] = acc[mm][nn][r] + bj;
      }
    }
  }
}

// ----------------------------------------------------------- attention -----
// One block = 128 q-rows of one (b,h). 4 waves x 32 rows. KV tile = 64 keys.
// Swapped QK^T: lane holds 16 keys of ONE query; softmax reduce = 15 fmax +
// 2 shfl; defer-max; exp2 units (K pre-scaled); P via cvt_pk to LDS; T14
// async staging of next K/V tile.
__global__ __launch_bounds__(256, 2) void attn_kernel(
    const short* __restrict__ Qb, const short* __restrict__ Kb,
    const short* __restrict__ Vt, short* __restrict__ Ao) {
  __shared__ __align__(16) char smem[25600];
  short* Kf = (short*)smem;                 // 8 planes x 64 lanes x 8 bf16
  short* Vf = (short*)(smem + 8192);
  short* Pl = (short*)(smem + 16384);       // 4 waves x [16 q][72]

  const int tid = threadIdx.x, lane = tid & 63, w = tid >> 6;
  const int c = lane & 15, g = lane >> 4;
  const int bh = blockIdx.x >> 3, qb = blockIdx.x & 7;
  const int bb = bh >> 4, h = bh & 15;
  const int q0 = qb * 128 + w * 32;

  bf16x8 qf[2][2];
#pragma unroll
  for (int m = 0; m < 2; ++m)
#pragma unroll
    for (int ks = 0; ks < 2; ++ks)
      qf[m][ks] = *(const bf16x8*)(Qb + (size_t)(bh * 1024 + q0 + m * 16 + c) * 64 + ks * 32 + 8 * g);

  f32x4 o[2][4] = {};
  float mrun[2] = {-3.0e38f, -3.0e38f};
  float lrun[2] = {0.f, 0.f};

  const int row_r = tid >> 2, seg = tid & 3;
  const short* kp = Kb + (size_t)(bh * 1024 + row_r) * 64 + seg * 16;
  const short* vp = Vt + (size_t)(bh * 64 + row_r) * 1024 + seg * 16;
  short *kdst0, *kdst1, *vdst0, *vdst1;
  {
    const int d0a = seg * 16, d0b = seg * 16 + 8;
    const int pa = (row_r >> 4) * 2 + (d0a >> 5);
    const int pb = (row_r >> 4) * 2 + (d0b >> 5);
    const int sa = (row_r & 15) + 16 * ((d0a & 31) >> 3);
    const int sb = (row_r & 15) + 16 * ((d0b & 31) >> 3);
    kdst0 = &Kf[(pa * 64 + sa) * 8]; kdst1 = &Kf[(pb * 64 + sb) * 8];
    vdst0 = &Vf[(pa * 64 + sa) * 8]; vdst1 = &Vf[(pb * 64 + sb) * 8];
  }

  uint32_t* plw = (uint32_t*)(Pl + w * 1152);
  const short* plr = Pl + w * 1152;

  auto compute = [&]() {
#pragma unroll
    for (int m = 0; m < 2; ++m) {
      f32x4 s[4];
#pragma unroll
      for (int kt = 0; kt < 4; ++kt) {
        f32x4 sa = {};
#pragma unroll
        for (int ks = 0; ks < 2; ++ks) {
          bf16x8 kb = *(const bf16x8*)&Kf[((kt * 2 + ks) * 64 + lane) * 8];
          sa = __builtin_amdgcn_mfma_f32_16x16x32_bf16(kb, qf[m][ks], sa, 0, 0, 0);
        }
        s[kt] = sa;
      }
      float vmax = s[0][0];
#pragma unroll
      for (int kt = 0; kt < 4; ++kt)
#pragma unroll
        for (int r = 0; r < 4; ++r) vmax = fmaxf(vmax, s[kt][r]);
      vmax = fmaxf(vmax, __shfl_xor(vmax, 16));
      vmax = fmaxf(vmax, __shfl_xor(vmax, 32));
      if (!__all(vmax <= mrun[m] + 8.0f)) {
        float mnew = fmaxf(mrun[m], vmax);
        float al = exp2_fast(mrun[m] - mnew);
        lrun[m] *= al;
#pragma unroll
        for (int dt = 0; dt < 4; ++dt) o[m][dt] *= al;
        mrun[m] = mnew;
      }
      float rs = 0.f;
#pragma unroll
      for (int kt = 0; kt < 4; ++kt) {
        float p0 = exp2_fast(s[kt][0] - mrun[m]);
        float p1 = exp2_fast(s[kt][1] - mrun[m]);
        float p2 = exp2_fast(s[kt][2] - mrun[m]);
        float p3 = exp2_fast(s[kt][3] - mrun[m]);
        rs += (p0 + p1) + (p2 + p3);
        u32x2 pk;
        pk[0] = cvt_pk_bf16(p0, p1);
        pk[1] = cvt_pk_bf16(p2, p3);
        *(u32x2*)&plw[c * 36 + kt * 8 + 2 * g] = pk;
      }
      rs += __shfl_xor(rs, 16);
      rs += __shfl_xor(rs, 32);
      lrun[m] += rs;
#pragma unroll
      for (int kk = 0; kk < 2; ++kk) {
        bf16x8 pb = *(const bf16x8*)(plr + c * 72 + kk * 32 + 8 * g);
#pragma unroll
        for (int dt = 0; dt < 4; ++dt) {
          bf16x8 vb = *(const bf16x8*)&Vf[((dt * 2 + kk) * 64 + lane) * 8];
          o[m][dt] = __builtin_amdgcn_mfma_f32_16x16x32_bf16(vb, pb, o[m][dt], 0, 0, 0);
        }
      }
    }
  };

  bf16x8 ka0, ka1, va0, va1, kc0, kc1, vc0, vc1;
  ka0 = *(const bf16x8*)(kp);     ka1 = *(const bf16x8*)(kp + 8);
  va0 = *(const bf16x8*)(vp);     va1 = *(const bf16x8*)(vp + 8);

  for (int t = 0; t < 16; t += 2) {
    __syncthreads();
    *(bf16x8*)kdst0 = ka0; *(bf16x8*)kdst1 = ka1;
    *(bf16x8*)vdst0 = va0; *(bf16x8*)vdst1 = va1;
    {
      const short* kpt = kp + (size_t)(t + 1) * 4096;
      const short* vpt = vp + (t + 1) * 64;
      kc0 = *(const bf16x8*)(kpt); kc1 = *(const bf16x8*)(kpt + 8);
      vc0 = *(const bf16x8*)(vpt); vc1 = *(const bf16x8*)(vpt + 8);
    }
    __syncthreads();
    compute();
    __syncthreads();
    *(bf16x8*)kdst0 = kc0; *(bf16x8*)kdst1 = kc1;
    *(bf16x8*)vdst0 = vc0; *(bf16x8*)vdst1 = vc1;
    if (t + 2 < 16) {
      const short* kpt = kp + (size_t)(t + 2) * 4096;
      const short* vpt = vp + (t + 2) * 64;
      ka0 = *(const bf16x8*)(kpt); ka1 = *(const bf16x8*)(kpt + 8);
      va0 = *(const bf16x8*)(vpt); va1 = *(const bf16x8*)(vpt + 8);
    }
    __syncthreads();
    compute();
  }

  __syncthreads();
  float* Osc = (float*)smem + w * (16 * 68);
  const int qrow = lane >> 2, dseg = (lane & 3) << 4;
#pragma unroll
  for (int m = 0; m < 2; ++m) {
    const float inv = 1.0f / lrun[m];
#pragma unroll
    for (int dt = 0; dt < 4; ++dt)
#pragma unroll
      for (int r = 0; r < 4; ++r)
        Osc[c * 68 + dt * 16 + 4 * g + r] = o[m][dt][r] * inv;
#pragma unroll
    for (int j = 0; j < 2; ++j) {
      f32x4 a0 = *(f32x4*)&Osc[qrow * 68 + dseg + j * 8];
      f32x4 a1 = *(f32x4*)&Osc[qrow * 68 + dseg + j * 8 + 4];
      bf16x8 ob;
      ob[0] = f32_bf16(a0[0]); ob[1] = f32_bf16(a0[1]);
      ob[2] = f32_bf16(a0[2]); ob[3] = f32_bf16(a0[3]);
      ob[4] = f32_bf16(a1[0]); ob[5] = f32_bf16(a1[1]);
      ob[6] = f32_bf16(a1[2]); ob[7] = f32_bf16(a1[3]);
      *(bf16x8*)(Ao + (size_t)(bb * 1024 + q0 + m * 16 + qrow) * 1024 + h * 64 + dseg + j * 8) = ob;
    }
    __syncthreads();
  }
}

// ------------------------------------------------------------- launch ------
extern "C" void kernel_launch(void* const* d_in, const int* in_sizes, int n_in,
                              void* d_out, int out_size, void* d_ws, size_t ws_size,
                              hipStream_t stream) {
  const float* x = (const float*)d_in[0];
  const float* w_qkv = (const float*)d_in[1];
  const float* b_qkv = (const float*)d_in[2];
  const float* w_proj = (const float*)d_in[3];
  const float* b_proj = (const float*)d_in[4];
  float* out = (float*)d_out;

  char* ws = (char*)d_ws;
  const size_t XB_OFF = 0;                       // 16 MB (reused as attn_out)
  const size_t WQKVT_OFF = 16777216;             // 6 MB
  const size_t WPROJT_OFF = WQKVT_OFF + 6291456; // 2 MB
  const size_t Q_OFF = WPROJT_OFF + 2097152;     // 16 MB
  const size_t K_OFF = Q_OFF + 16777216;         // 16 MB
  const size_t VT_OFF = K_OFF + 16777216;        // 16 MB
  short* xb = (short*)(ws + XB_OFF);
  short* wqkvT = (short*)(ws + WQKVT_OFF);
  short* wprojT = (short*)(ws + WPROJT_OFF);
  short* Qb = (short*)(ws + Q_OFF);
  short* Kb = (short*)(ws + K_OFF);
  short* Vt = (short*)(ws + VT_OFF);
  short* attn_o = xb;  // xb dead after GEMM1

  convert_x_kernel<<<dim3(4096), dim3(256), 0, stream>>>(x, xb);
  transpose_w_kernel<<<dim3(48, 16), dim3(256), 0, stream>>>(w_qkv, wqkvT, 3072);
  transpose_w_kernel<<<dim3(16, 16), dim3(256), 0, stream>>>(w_proj, wprojT, 1024);
  // GEMM1: 8192x3072x1024, 256x128 tiles -> 32x24 = 768 blocks = 3 exact rounds
  gemm8_kernel<0><<<dim3(768), dim3(512), 0, stream>>>(
      xb, wqkvT, b_qkv, Qb, Kb, Vt, nullptr, 24);
  attn_kernel<<<dim3(1024), dim3(256), 0, stream>>>(Qb, Kb, Vt, attn_o);
  // GEMM2: 8192x1024x1024, 256x128 tiles -> 32x8 = 256 blocks = 1 exact round
  gemm8_kernel<1><<<dim3(256), dim3(512), 0, stream>>>(
      attn_o, wprojT, b_proj, nullptr, nullptr, nullptr, out, 8);
}

// Round 7
// 273.269 us; speedup vs baseline: 1.1406x; 1.0422x over previous
//
#include <hip/hip_runtime.h>
#include <stdint.h>

// ---------------------------------------------------------------------------
// MultiHeadSelfAttention: B=8, N=1024, D=1024, H=16, hd=64, scale=0.125
// Pipeline: [x->bf16, wT->bf16] -> GEMM1(qkv + bias, scatter Q/K(pre-scaled)/Vt)
//           -> flash attention (swapped QK^T, in-lane softmax, exp2 units)
//           -> GEMM2(proj + bias, fp32 out)
// GEMMs (R7): 128x128 tile, 4 waves, double-buffered LDS (64 KB) -> 2
// blocks/CU for cross-block stall overlap; counted vmcnt(8) + barrier before
// dependent ds_reads (R4-verified skeleton); XOR-swizzled LDS (0 conflicts,
// R5-verified); exact grid rounds (1536 = 3, 512 = 1).
// ---------------------------------------------------------------------------

typedef short bf16x8 __attribute__((ext_vector_type(8)));
typedef float f32x4 __attribute__((ext_vector_type(4)));
typedef uint32_t u32x2 __attribute__((ext_vector_type(2)));

__device__ __forceinline__ short f32_bf16(float f) {
  uint32_t u = __builtin_bit_cast(uint32_t, f);
  u += 0x7FFFu + ((u >> 16) & 1u);   // round-to-nearest-even (no NaN inputs)
  return (short)(u >> 16);
}

__device__ __forceinline__ float exp2_fast(float x) {
  float r; asm("v_exp_f32 %0, %1" : "=v"(r) : "v"(x)); return r;
}

__device__ __forceinline__ uint32_t cvt_pk_bf16(float lo, float hi) {
  uint32_t r;
  asm("v_cvt_pk_bf16_f32 %0, %1, %2" : "=v"(r) : "v"(lo), "v"(hi));
  return r;
}

__device__ __forceinline__ void gload_lds16(const void* g, void* l) {
  __builtin_amdgcn_global_load_lds(
      (const __attribute__((address_space(1))) uint32_t*)g,
      (__attribute__((address_space(3))) uint32_t*)l, 16, 0, 0);
}

// ---------------------------------------------------------------- prep ------
__global__ __launch_bounds__(256) void convert_x_kernel(
    const float* __restrict__ x, short* __restrict__ xb) {
  int i = blockIdx.x * 256 + threadIdx.x;
  const float4 f0 = ((const float4*)x)[i * 2];
  const float4 f1 = ((const float4*)x)[i * 2 + 1];
  bf16x8 o;
  o[0] = f32_bf16(f0.x); o[1] = f32_bf16(f0.y);
  o[2] = f32_bf16(f0.z); o[3] = f32_bf16(f0.w);
  o[4] = f32_bf16(f1.x); o[5] = f32_bf16(f1.y);
  o[6] = f32_bf16(f1.z); o[7] = f32_bf16(f1.w);
  ((bf16x8*)xb)[i] = o;
}

// w: fp32 [1024][N] -> wt: bf16 [N][1024]
__global__ __launch_bounds__(256) void transpose_w_kernel(
    const float* __restrict__ w, short* __restrict__ wt, int N) {
  __shared__ float tile[64][65];
  const int n0 = blockIdx.x * 64, k0 = blockIdx.y * 64;
  const int tr = threadIdx.x >> 6, tc = threadIdx.x & 63;
#pragma unroll
  for (int i = 0; i < 16; ++i) {
    int k = tr + i * 4;
    tile[k][tc] = w[(size_t)(k0 + k) * N + n0 + tc];
  }
  __syncthreads();
#pragma unroll
  for (int i = 0; i < 16; ++i) {
    int a = tr + i * 4;
    wt[(size_t)(n0 + a) * 1024 + k0 + tc] = f32_bf16(tile[tc][a]);
  }
}

// ------------------------------------------------- pipelined 128^2 GEMM ----
// BM=BN=128, BK=64, 256 threads (4 waves 2x2), per-wave 64x64, acc[4][4].
// Double-buffered 64 KB LDS -> 2 blocks/CU: co-resident block's MFMA covers
// this block's vmcnt/barrier stalls (m114 implicit overlap).
// Per K-tile: stage ALL 8 chunks of tile t+1 into buf^1, vmcnt(8) [drains
// tile t's chunks, issued one tile ago] + s_barrier, then ds_reads + 2
// m-phases x 16 MFMA; end barrier closes WAR on buf.
// LDS conflict-free via XOR swizzle: LDS[r][s] holds granule s^(r&7).
// EPI=0: qkv scatter epilogue (bias, Q/K-prescaled/Vt). EPI=1: fp32 out+bias.
template <int EPI>
__global__ __launch_bounds__(256, 2) void gemm4_kernel(
    const short* __restrict__ A, const short* __restrict__ Bt,
    const float* __restrict__ bias, short* __restrict__ Qb,
    short* __restrict__ Kb, short* __restrict__ Vt, float* __restrict__ out,
    int NTN) {
  __shared__ short Asm[2][128 * 64];
  __shared__ short Bsm[2][128 * 64];

  const int tid = threadIdx.x;
  const int lane = tid & 63;
  const int w = tid >> 6;
  const int wr = w >> 1, wc = w & 1;
  const int c = lane & 15, g = lane >> 4;

  // XCD-bijective swizzle (grid % 8 == 0 for both instantiations)
  const int nwg = gridDim.x;
  const int wg = (blockIdx.x & 7) * (nwg >> 3) + (blockIdx.x >> 3);
  const int tm = wg / NTN, tn = wg % NTN;
  const int m0 = tm * 128, n0 = tn * 128;

  f32x4 acc[4][4] = {};

  // 8 chunks/tile/thread-issue: 4 A + 4 B (128x64 each, 16B granules)
  auto stage = [&](int dbuf, int kk0) {
#pragma unroll
    for (int ci = 0; ci < 4; ++ci) {
      const int p = ci * 256 + tid;
      const int r = p >> 3, s = p & 7;
      gload_lds16(A + (size_t)(m0 + r) * 1024 + kk0 + ((s ^ (r & 7)) * 8),
                  &Asm[dbuf][p * 8]);
    }
#pragma unroll
    for (int ci = 0; ci < 4; ++ci) {
      const int p = ci * 256 + tid;
      const int r = p >> 3, s = p & 7;
      gload_lds16(Bt + (size_t)(n0 + r) * 1024 + kk0 + ((s ^ (r & 7)) * 8),
                  &Bsm[dbuf][p * 8]);
    }
  };

  stage(0, 0);

  for (int t = 0; t < 16; ++t) {
    const int buf = t & 1;
    if (t < 15) {
      stage(buf ^ 1, (t + 1) * 64);
      asm volatile("s_waitcnt vmcnt(8)" ::: "memory");  // drain tile t only
    } else {
      asm volatile("s_waitcnt vmcnt(0)" ::: "memory");
    }
    __builtin_amdgcn_s_barrier();        // all waves' tile-t chunks resident
    __builtin_amdgcn_sched_barrier(0);

    // B-frags: read once, held across both m-phases
    bf16x8 bfr[4][2];
#pragma unroll
    for (int jn = 0; jn < 4; ++jn) {
      const int S = wc * 64 + jn * 16 + c;
#pragma unroll
      for (int kk = 0; kk < 2; ++kk)
        bfr[jn][kk] = *(const bf16x8*)&Bsm[buf][S * 64 + (((kk * 4 + g) ^ (c & 7)) * 8)];
    }
#pragma unroll
    for (int mq = 0; mq < 2; ++mq) {
      bf16x8 af[2][2];
#pragma unroll
      for (int mm = 0; mm < 2; ++mm) {
        const int R = wr * 64 + (mq * 2 + mm) * 16 + c;
#pragma unroll
        for (int kk = 0; kk < 2; ++kk)
          af[mm][kk] = *(const bf16x8*)&Asm[buf][R * 64 + (((kk * 4 + g) ^ (c & 7)) * 8)];
      }
      asm volatile("s_waitcnt lgkmcnt(0)" ::: "memory");
      __builtin_amdgcn_sched_barrier(0);  // rule #18
      __builtin_amdgcn_s_setprio(1);
#pragma unroll
      for (int mm = 0; mm < 2; ++mm)
#pragma unroll
        for (int jn = 0; jn < 4; ++jn)
#pragma unroll
          for (int kk = 0; kk < 2; ++kk)
            acc[mq * 2 + mm][jn] = __builtin_amdgcn_mfma_f32_16x16x32_bf16(
                af[mm][kk], bfr[jn][kk], acc[mq * 2 + mm][jn], 0, 0, 0);
      __builtin_amdgcn_s_setprio(0);
    }
    __builtin_amdgcn_s_barrier();        // reads of buf done before restaging
    __builtin_amdgcn_sched_barrier(0);
  }

  // epilogue
#pragma unroll
  for (int mm = 0; mm < 4; ++mm) {
    const int i_base = m0 + wr * 64 + mm * 16 + 4 * g;
#pragma unroll
    for (int nn = 0; nn < 4; ++nn) {
      const int j = n0 + wc * 64 + nn * 16 + c;
      const float bj = bias[j];
      if (EPI == 0) {
        const int three = j >> 10, rem = j & 1023, h = rem >> 6, d = rem & 63;
        const float sc = (three == 1) ? 0.18033688f : 1.0f;  // 0.125*log2(e)
#pragma unroll
        for (int r = 0; r < 4; ++r) {
          const int i = i_base + r;
          const int bb = i >> 10, nnq = i & 1023;
          const int bh = bb * 16 + h;
          const short bv = f32_bf16((acc[mm][nn][r] + bj) * sc);
          if (three == 0)
            Qb[(size_t)(bh * 1024 + nnq) * 64 + d] = bv;
          else if (three == 1)
            Kb[(size_t)(bh * 1024 + nnq) * 64 + d] = bv;
          else
            Vt[(size_t)(bh * 64 + d) * 1024 + nnq] = bv;
        }
      } else {
#pragma unroll
        for (int r = 0; r < 4; ++r)
          out[(size_t)(i_base + r) * 1024 + j] = acc[mm][nn][r] + bj;
      }
    }
  }
}

// ----------------------------------------------------------- attention -----
// One block = 128 q-rows of one (b,h). 4 waves x 32 rows. KV tile = 64 keys.
// Swapped QK^T: lane holds 16 keys of ONE query; softmax reduce = 15 fmax +
// 2 shfl; defer-max; exp2 units (K pre-scaled); P via cvt_pk to LDS; T14
// async staging of next K/V tile.
__global__ __launch_bounds__(256, 2) void attn_kernel(
    const short* __restrict__ Qb, const short* __restrict__ Kb,
    const short* __restrict__ Vt, short* __restrict__ Ao) {
  __shared__ __align__(16) char smem[25600];
  short* Kf = (short*)smem;                 // 8 planes x 64 lanes x 8 bf16
  short* Vf = (short*)(smem + 8192);
  short* Pl = (short*)(smem + 16384);       // 4 waves x [16 q][72]

  const int tid = threadIdx.x, lane = tid & 63, w = tid >> 6;
  const int c = lane & 15, g = lane >> 4;
  const int bh = blockIdx.x >> 3, qb = blockIdx.x & 7;
  const int bb = bh >> 4, h = bh & 15;
  const int q0 = qb * 128 + w * 32;

  bf16x8 qf[2][2];
#pragma unroll
  for (int m = 0; m < 2; ++m)
#pragma unroll
    for (int ks = 0; ks < 2; ++ks)
      qf[m][ks] = *(const bf16x8*)(Qb + (size_t)(bh * 1024 + q0 + m * 16 + c) * 64 + ks * 32 + 8 * g);

  f32x4 o[2][4] = {};
  float mrun[2] = {-3.0e38f, -3.0e38f};
  float lrun[2] = {0.f, 0.f};

  const int row_r = tid >> 2, seg = tid & 3;
  const short* kp = Kb + (size_t)(bh * 1024 + row_r) * 64 + seg * 16;
  const short* vp = Vt + (size_t)(bh * 64 + row_r) * 1024 + seg * 16;
  short *kdst0, *kdst1, *vdst0, *vdst1;
  {
    const int d0a = seg * 16, d0b = seg * 16 + 8;
    const int pa = (row_r >> 4) * 2 + (d0a >> 5);
    const int pb = (row_r >> 4) * 2 + (d0b >> 5);
    const int sa = (row_r & 15) + 16 * ((d0a & 31) >> 3);
    const int sb = (row_r & 15) + 16 * ((d0b & 31) >> 3);
    kdst0 = &Kf[(pa * 64 + sa) * 8]; kdst1 = &Kf[(pb * 64 + sb) * 8];
    vdst0 = &Vf[(pa * 64 + sa) * 8]; vdst1 = &Vf[(pb * 64 + sb) * 8];
  }

  uint32_t* plw = (uint32_t*)(Pl + w * 1152);
  const short* plr = Pl + w * 1152;

  auto compute = [&]() {
#pragma unroll
    for (int m = 0; m < 2; ++m) {
      f32x4 s[4];
#pragma unroll
      for (int kt = 0; kt < 4; ++kt) {
        f32x4 sa = {};
#pragma unroll
        for (int ks = 0; ks < 2; ++ks) {
          bf16x8 kb = *(const bf16x8*)&Kf[((kt * 2 + ks) * 64 + lane) * 8];
          sa = __builtin_amdgcn_mfma_f32_16x16x32_bf16(kb, qf[m][ks], sa, 0, 0, 0);
        }
        s[kt] = sa;
      }
      float vmax = s[0][0];
#pragma unroll
      for (int kt = 0; kt < 4; ++kt)
#pragma unroll
        for (int r = 0; r < 4; ++r) vmax = fmaxf(vmax, s[kt][r]);
      vmax = fmaxf(vmax, __shfl_xor(vmax, 16));
      vmax = fmaxf(vmax, __shfl_xor(vmax, 32));
      if (!__all(vmax <= mrun[m] + 8.0f)) {
        float mnew = fmaxf(mrun[m], vmax);
        float al = exp2_fast(mrun[m] - mnew);
        lrun[m] *= al;
#pragma unroll
        for (int dt = 0; dt < 4; ++dt) o[m][dt] *= al;
        mrun[m] = mnew;
      }
      float rs = 0.f;
#pragma unroll
      for (int kt = 0; kt < 4; ++kt) {
        float p0 = exp2_fast(s[kt][0] - mrun[m]);
        float p1 = exp2_fast(s[kt][1] - mrun[m]);
        float p2 = exp2_fast(s[kt][2] - mrun[m]);
        float p3 = exp2_fast(s[kt][3] - mrun[m]);
        rs += (p0 + p1) + (p2 + p3);
        u32x2 pk;
        pk[0] = cvt_pk_bf16(p0, p1);
        pk[1] = cvt_pk_bf16(p2, p3);
        *(u32x2*)&plw[c * 36 + kt * 8 + 2 * g] = pk;
      }
      rs += __shfl_xor(rs, 16);
      rs += __shfl_xor(rs, 32);
      lrun[m] += rs;
#pragma unroll
      for (int kk = 0; kk < 2; ++kk) {
        bf16x8 pb = *(const bf16x8*)(plr + c * 72 + kk * 32 + 8 * g);
#pragma unroll
        for (int dt = 0; dt < 4; ++dt) {
          bf16x8 vb = *(const bf16x8*)&Vf[((dt * 2 + kk) * 64 + lane) * 8];
          o[m][dt] = __builtin_amdgcn_mfma_f32_16x16x32_bf16(vb, pb, o[m][dt], 0, 0, 0);
        }
      }
    }
  };

  bf16x8 ka0, ka1, va0, va1, kc0, kc1, vc0, vc1;
  ka0 = *(const bf16x8*)(kp);     ka1 = *(const bf16x8*)(kp + 8);
  va0 = *(const bf16x8*)(vp);     va1 = *(const bf16x8*)(vp + 8);

  for (int t = 0; t < 16; t += 2) {
    __syncthreads();
    *(bf16x8*)kdst0 = ka0; *(bf16x8*)kdst1 = ka1;
    *(bf16x8*)vdst0 = va0; *(bf16x8*)vdst1 = va1;
    {
      const short* kpt = kp + (size_t)(t + 1) * 4096;
      const short* vpt = vp + (t + 1) * 64;
      kc0 = *(const bf16x8*)(kpt); kc1 = *(const bf16x8*)(kpt + 8);
      vc0 = *(const bf16x8*)(vpt); vc1 = *(const bf16x8*)(vpt + 8);
    }
    __syncthreads();
    compute();
    __syncthreads();
    *(bf16x8*)kdst0 = kc0; *(bf16x8*)kdst1 = kc1;
    *(bf16x8*)vdst0 = vc0; *(bf16x8*)vdst1 = vc1;
    if (t + 2 < 16) {
      const short* kpt = kp + (size_t)(t + 2) * 4096;
      const short* vpt = vp + (t + 2) * 64;
      ka0 = *(const bf16x8*)(kpt); ka1 = *(const bf16x8*)(kpt + 8);
      va0 = *(const bf16x8*)(vpt); va1 = *(const bf16x8*)(vpt + 8);
    }
    __syncthreads();
    compute();
  }

  __syncthreads();
  float* Osc = (float*)smem + w * (16 * 68);
  const int qrow = lane >> 2, dseg = (lane & 3) << 4;
#pragma unroll
  for (int m = 0; m < 2; ++m) {
    const float inv = 1.0f / lrun[m];
#pragma unroll
    for (int dt = 0; dt < 4; ++dt)
#pragma unroll
      for (int r = 0; r < 4; ++r)
        Osc[c * 68 + dt * 16 + 4 * g + r] = o[m][dt][r] * inv;
#pragma unroll
    for (int j = 0; j < 2; ++j) {
      f32x4 a0 = *(f32x4*)&Osc[qrow * 68 + dseg + j * 8];
      f32x4 a1 = *(f32x4*)&Osc[qrow * 68 + dseg + j * 8 + 4];
      bf16x8 ob;
      ob[0] = f32_bf16(a0[0]); ob[1] = f32_bf16(a0[1]);
      ob[2] = f32_bf16(a0[2]); ob[3] = f32_bf16(a0[3]);
      ob[4] = f32_bf16(a1[0]); ob[5] = f32_bf16(a1[1]);
      ob[6] = f32_bf16(a1[2]); ob[7] = f32_bf16(a1[3]);
      *(bf16x8*)(Ao + (size_t)(bb * 1024 + q0 + m * 16 + qrow) * 1024 + h * 64 + dseg + j * 8) = ob;
    }
    __syncthreads();
  }
}

// ------------------------------------------------------------- launch ------
extern "C" void kernel_launch(void* const* d_in, const int* in_sizes, int n_in,
                              void* d_out, int out_size, void* d_ws, size_t ws_size,
                              hipStream_t stream) {
  const float* x = (const float*)d_in[0];
  const float* w_qkv = (const float*)d_in[1];
  const float* b_qkv = (const float*)d_in[2];
  const float* w_proj = (const float*)d_in[3];
  const float* b_proj = (const float*)d_in[4];
  float* out = (float*)d_out;

  char* ws = (char*)d_ws;
  const size_t XB_OFF = 0;                       // 16 MB (reused as attn_out)
  const size_t WQKVT_OFF = 16777216;             // 6 MB
  const size_t WPROJT_OFF = WQKVT_OFF + 6291456; // 2 MB
  const size_t Q_OFF = WPROJT_OFF + 2097152;     // 16 MB
  const size_t K_OFF = Q_OFF + 16777216;         // 16 MB
  const size_t VT_OFF = K_OFF + 16777216;        // 16 MB
  short* xb = (short*)(ws + XB_OFF);
  short* wqkvT = (short*)(ws + WQKVT_OFF);
  short* wprojT = (short*)(ws + WPROJT_OFF);
  short* Qb = (short*)(ws + Q_OFF);
  short* Kb = (short*)(ws + K_OFF);
  short* Vt = (short*)(ws + VT_OFF);
  short* attn_o = xb;  // xb dead after GEMM1

  convert_x_kernel<<<dim3(4096), dim3(256), 0, stream>>>(x, xb);
  transpose_w_kernel<<<dim3(48, 16), dim3(256), 0, stream>>>(w_qkv, wqkvT, 3072);
  transpose_w_kernel<<<dim3(16, 16), dim3(256), 0, stream>>>(w_proj, wprojT, 1024);
  // GEMM1: 8192x3072x1024, 128x128 tiles -> 64x24 = 1536 blocks = 3 rounds @2/CU
  gemm4_kernel<0><<<dim3(1536), dim3(256), 0, stream>>>(
      xb, wqkvT, b_qkv, Qb, Kb, Vt, nullptr, 24);
  attn_kernel<<<dim3(1024), dim3(256), 0, stream>>>(Qb, Kb, Vt, attn_o);
  // GEMM2: 8192x1024x1024, 128x128 tiles -> 64x8 = 512 blocks = 1 round @2/CU
  gemm4_kernel<1><<<dim3(512), dim3(256), 0, stream>>>(
      attn_o, wprojT, b_proj, nullptr, nullptr, nullptr, out, 8);
}